// Round 3
// baseline (292.348 us; speedup 1.0000x reference)
//
#include <hip/hip_runtime.h>

// ---------------------------------------------------------------------------
// ANHPMultiHeadAttention: fused QKV projection + exp-scored causal attention
// B=8, S=1024, FEAT=HID=1024, H=8, DH=128.
//
// R3 changes vs R2:
//  - ATTN rewritten barrier-free: one wave per block (64 thr), 32 q-rows,
//    K/V fragments read DIRECTLY from global (L2-resident, XCD-swizzled
//    block mapping), only P round-trips through 2KB LDS. S^T = MFMA(kf,qf)
//    makes P-writes b64; O^T = MFMA(vf,pa) makes output stores float4.
//    Per-wave causal key range (kend = qw+32) removes masked-tile work.
//  - GEMM: Q/K epilogue uses swapped-operand MFMA (C^T) -> 4 consecutive d
//    per lane -> ushort4 stores (16) instead of scalar b16 stores (64).
//  - cast_x + transpose_w merged into one launch.
// ---------------------------------------------------------------------------

typedef __bf16 bf16x8 __attribute__((ext_vector_type(8)));
typedef float floatx4 __attribute__((ext_vector_type(4)));
typedef unsigned short u16;
typedef unsigned int u32;

#define RSCALE 0.08838834764831845f   // 1/sqrt(128)

__device__ __forceinline__ u16 f2b(float f) {       // fp32 -> bf16 bits, RNE
  union { float f; unsigned u; } v; v.f = f;
  return (u16)((v.u + 0x7FFFu + ((v.u >> 16) & 1u)) >> 16);
}

// async global->LDS, 16B per lane. LDS dst = wave-uniform base + lane*16.
__device__ __forceinline__ void gld_lds16(const void* g, void* l) {
  __builtin_amdgcn_global_load_lds(
      (const __attribute__((address_space(1))) unsigned*)g,
      (__attribute__((address_space(3))) unsigned*)l, 16, 0, 0);
}

#define MFMA16(a, b, c) __builtin_amdgcn_mfma_f32_16x16x32_bf16(a, b, c, 0, 0, 0)

// ---------------------------------------------------------------------------
// Kernel 1: prep = cast X (blocks 0..8191) + transpose W (blocks 8192..11263)
// ---------------------------------------------------------------------------
__global__ __launch_bounds__(256) void prep_kernel(
    const float4* __restrict__ X, u16* __restrict__ Xb,
    const float* __restrict__ Wq, const float* __restrict__ Wk,
    const float* __restrict__ Wv, u16* __restrict__ Wtb) {
  if (blockIdx.x < 8192) {
    unsigned i = blockIdx.x * 256u + threadIdx.x;
    float4 v = X[i];
    ushort4 o;
    o.x = f2b(v.x); o.y = f2b(v.y); o.z = f2b(v.z); o.w = f2b(v.w);
    *reinterpret_cast<ushort4*>(Xb + 4u * i) = o;
  } else {
    const int bid = blockIdx.x - 8192;          // 0..3071
    const int mat = bid >> 10;                  // 1024 blocks per matrix
    const int bx = bid & 31, by = (bid >> 5) & 31;
    const float* W = (mat == 0) ? Wq : (mat == 1) ? Wk : Wv;
    u16* Wt = Wtb + (size_t)mat * (1024u * 1024u);
    __shared__ u16 tile[32][33];
    const int x = threadIdx.x & 31, y = threadIdx.x >> 5;
    const int kt = bx * 32, nt = by * 32;
#pragma unroll
    for (int i = 0; i < 4; ++i)
      tile[y + 8 * i][x] = f2b(W[(size_t)(kt + y + 8 * i) * 1024 + nt + x]);
    __syncthreads();
#pragma unroll
    for (int i = 0; i < 4; ++i)
      Wt[(size_t)(nt + y + 8 * i) * 1024 + kt + x] = tile[x][y + 8 * i];
  }
}

// ---------------------------------------------------------------------------
// Kernel 2: QKV GEMM. 128x128 tile, BK=64, XOR-8 swizzled LDS (0 conflicts).
// grid (64, 8, 3): z selects {Q,K,V}. Q,K stored [B,H,S,DH]; V [B,H,DH,S].
// For Q,K the MFMA operands are swapped (C^T) so each lane's 4 acc regs are
// 4 consecutive d -> 8B packed stores.
// ---------------------------------------------------------------------------
__global__ __launch_bounds__(256) void gemm_qkv_kernel(
    const u16* __restrict__ Xb, const u16* __restrict__ Wtb,
    const float* __restrict__ bq, const float* __restrict__ bk,
    const float* __restrict__ bv, u16* __restrict__ Qh, u16* __restrict__ Kh,
    u16* __restrict__ Vt) {
  const int mat = blockIdx.z;
  const bool matQK = (mat < 2);
  const u16* __restrict__ Wt = Wtb + (size_t)mat * (1024u * 1024u);
  const float* __restrict__ bias = (mat == 0) ? bq : (mat == 1) ? bk : bv;

  const int m0 = blockIdx.x * 128;
  const int n0 = blockIdx.y * 128;

  __shared__ u16 As[128 * 64];   // [m][k] 16KB, 128B rows, xor8-swizzled
  __shared__ u16 Bs[128 * 64];   // [n][k] 16KB

  const int tid = threadIdx.x;
  const int wid = tid >> 6;
  const int lane = tid & 63;
  const int quad = lane >> 4;
  const int l16 = lane & 15;
  const int l8 = lane & 7;
  const int wm = (wid & 1) * 64;
  const int wn = (wid >> 1) * 64;

  const floatx4 z4 = {0.f, 0.f, 0.f, 0.f};
  floatx4 acc[4][4];
#pragma unroll
  for (int i = 0; i < 4; ++i)
#pragma unroll
    for (int j = 0; j < 4; ++j) acc[i][j] = z4;

  const int srow = wid * 32;
  const int lrow = lane >> 3;            // 0..7 within call
  const int gblk = l8 ^ lrow;            // xor8 swizzle

  for (int k0 = 0; k0 < 1024; k0 += 64) {
    __syncthreads();
#pragma unroll
    for (int c = 0; c < 4; ++c) {
      const int row = srow + c * 8 + lrow;
      gld_lds16(Xb + (size_t)(m0 + row) * 1024 + k0 + gblk * 8,
                As + (srow + c * 8) * 64);
      gld_lds16(Wt + (size_t)(n0 + row) * 1024 + k0 + gblk * 8,
                Bs + (srow + c * 8) * 64);
    }
    __syncthreads();

#pragma unroll
    for (int c = 0; c < 2; ++c) {
      const int phys = ((c * 4 + quad) ^ (l16 & 7)) * 8;
      bf16x8 af[4], bfr[4];
#pragma unroll
      for (int i = 0; i < 4; ++i)
        af[i] = *(const bf16x8*)(As + (wm + i * 16 + l16) * 64 + phys);
#pragma unroll
      for (int j = 0; j < 4; ++j)
        bfr[j] = *(const bf16x8*)(Bs + (wn + j * 16 + l16) * 64 + phys);
      if (matQK) {
#pragma unroll
        for (int i = 0; i < 4; ++i)
#pragma unroll
          for (int j = 0; j < 4; ++j)
            acc[i][j] = MFMA16(bfr[j], af[i], acc[i][j]);   // C^T
      } else {
#pragma unroll
        for (int i = 0; i < 4; ++i)
#pragma unroll
          for (int j = 0; j < 4; ++j)
            acc[i][j] = MFMA16(af[i], bfr[j], acc[i][j]);
      }
    }
  }

  const int b = m0 >> 10;
  const int h = n0 >> 7;

  if (matQK) {
    // C^T layout: col(l16) = m (s), row(quad*4+r) = n (d) -> 4 consecutive d.
    u16* outp = (mat == 0 ? Qh : Kh) + (size_t)(b * 8 + h) * 1024 * 128;
    float4 bias4[4];
#pragma unroll
    for (int j = 0; j < 4; ++j)
      bias4[j] = *(const float4*)(bias + n0 + wn + j * 16 + quad * 4);
#pragma unroll
    for (int i = 0; i < 4; ++i) {
      const int s = (m0 & 1023) + wm + i * 16 + l16;
#pragma unroll
      for (int j = 0; j < 4; ++j) {
        const int d0 = wn + j * 16 + quad * 4;
        ushort4 pk;
        pk.x = f2b(acc[i][j][0] + bias4[j].x);
        pk.y = f2b(acc[i][j][1] + bias4[j].y);
        pk.z = f2b(acc[i][j][2] + bias4[j].z);
        pk.w = f2b(acc[i][j][3] + bias4[j].w);
        *(ushort4*)(outp + (size_t)s * 128 + d0) = pk;
      }
    }
  } else {
    // V^T: out[((b*8+h)*128 + d)*1024 + s]; 4 regs = 4 consecutive s.
    u16* outp = Vt + (size_t)(b * 8 + h) * 128 * 1024;
    const int sbase = (m0 & 1023) + wm;
    float bv4[4];
#pragma unroll
    for (int j = 0; j < 4; ++j) bv4[j] = bias[n0 + wn + j * 16 + l16];
#pragma unroll
    for (int i = 0; i < 4; ++i)
#pragma unroll
      for (int j = 0; j < 4; ++j) {
        const int d = wn + j * 16 + l16;
        const int s = sbase + i * 16 + quad * 4;
        ushort4 pk;
        pk.x = f2b(acc[i][j][0] + bv4[j]);
        pk.y = f2b(acc[i][j][1] + bv4[j]);
        pk.z = f2b(acc[i][j][2] + bv4[j]);
        pk.w = f2b(acc[i][j][3] + bv4[j]);
        *(ushort4*)(outp + (size_t)d * 1024 + s) = pk;
      }
  }
}

// ---------------------------------------------------------------------------
// Kernel 3: attention, barrier-free. grid 2048 blocks x 64 threads (1 wave).
// Each wave: 32 q-rows of one (b,h); keys [0, qw+32) (per-wave causal range).
// K/V frags direct from global (L2); P via 2KB LDS (b64 write, b128 read).
// S^T = MFMA(kf, qf): lane = (4 keys, 1 qrow). O^T = MFMA(vf, pa):
// lane = (4 consecutive d, 1 qrow) -> float4 stores.
// Block swizzle: xcd = id&7 owns bh in [8*xcd, 8*xcd+8) -> ~4MB K+V per XCD
// L2; heavy q-tiles dispatch first within each xcd.
// ---------------------------------------------------------------------------
__global__ __launch_bounds__(64, 3) void attn_kernel(const u16* __restrict__ Qh,
                                                     const u16* __restrict__ Kh,
                                                     const u16* __restrict__ Vt,
                                                     float* __restrict__ out) {
  const int id = blockIdx.x;
  const int bh = (id & 7) * 8 + ((id >> 3) & 7);
  const int qidx = 31 - (id >> 6);        // heavy tiles first (LPT)
  const int qw = qidx * 32;

  const int lane = threadIdx.x & 63;
  const int quad = lane >> 4;
  const int l16 = lane & 15;

  __shared__ u16 Ps[32 * 32];             // 2KB; rows 64B; 16B-unit swizzle

  const u16* __restrict__ Qbase = Qh + (size_t)bh * 1024 * 128;
  const u16* __restrict__ Kbase = Kh + (size_t)bh * 1024 * 128;
  const u16* __restrict__ Vbase = Vt + (size_t)bh * 128 * 1024;

  // Q B-frags: B[k=d(quad*8+j)][n=qrow(l16)]
  bf16x8 qf[2][4];
#pragma unroll
  for (int nt = 0; nt < 2; ++nt)
#pragma unroll
    for (int c = 0; c < 4; ++c)
      qf[nt][c] = *(const bf16x8*)(Qbase + (size_t)(qw + nt * 16 + l16) * 128 +
                                   c * 32 + quad * 8);

  const floatx4 z4 = {0.f, 0.f, 0.f, 0.f};
  floatx4 o[8][2];
#pragma unroll
  for (int dt = 0; dt < 8; ++dt) { o[dt][0] = z4; o[dt][1] = z4; }
  float lacc[2] = {0.f, 0.f};

  const int psw = (quad >> 1) ^ (l16 & 3);        // write unit base (f=0)
  const int psr = quad ^ (l16 & 3);               // read unit

  for (int k0 = 0; k0 <= qw; k0 += 32) {
    // --- K A-frags: A[m=key(l16)][k=d(quad*8+j)] ---
    bf16x8 kf[2][4];
#pragma unroll
    for (int f = 0; f < 2; ++f)
#pragma unroll
      for (int c = 0; c < 4; ++c)
        kf[f][c] = *(const bf16x8*)(Kbase +
                                    (size_t)(k0 + f * 16 + l16) * 128 +
                                    c * 32 + quad * 8);

    // --- S^T tiles + exp + pack + Ps write ---
#pragma unroll
    for (int f = 0; f < 2; ++f)
#pragma unroll
      for (int nt = 0; nt < 2; ++nt) {
        floatx4 st = z4;
#pragma unroll
        for (int c = 0; c < 4; ++c) st = MFMA16(kf[f][c], qf[nt][c], st);
        const int qrow = qw + nt * 16 + l16;
        const int kb = k0 + f * 16 + quad * 4;
        float p[4];
#pragma unroll
        for (int r = 0; r < 4; ++r) {
          const float e = fminf(__expf(st[r] * RSCALE), 85.f);
          p[r] = (kb + r > qrow) ? 0.f : __expf(e);
        }
        lacc[nt] += (p[0] + p[1]) + (p[2] + p[3]);
        uint2 pk;
        pk.x = (u32)f2b(p[0]) | ((u32)f2b(p[1]) << 16);
        pk.y = (u32)f2b(p[2]) | ((u32)f2b(p[3]) << 16);
        *(uint2*)((char*)Ps + (nt * 16 + l16) * 64 +
                  ((f * 2 + (quad >> 1)) ^ (l16 & 3)) * 16 + (quad & 1) * 8) = pk;
      }
    asm volatile("s_waitcnt lgkmcnt(0)" ::: "memory");  // wave-local P ready

    // --- PV: O^T += V^T-frag x P^T-frag ---
    bf16x8 pa[2];
#pragma unroll
    for (int nt = 0; nt < 2; ++nt)
      pa[nt] = *(const bf16x8*)((char*)Ps + (nt * 16 + l16) * 64 + psr * 16);
#pragma unroll
    for (int dt = 0; dt < 8; ++dt) {
      const bf16x8 vf = *(const bf16x8*)(Vbase +
                                         (size_t)(dt * 16 + l16) * 1024 +
                                         k0 + quad * 8);
      o[dt][0] = MFMA16(vf, pa[0], o[dt][0]);
      o[dt][1] = MFMA16(vf, pa[1], o[dt][1]);
    }
  }
  (void)psw;

  // row-sum: lane holds partial over its quad's keys; reduce across quads.
  float linv[2];
#pragma unroll
  for (int nt = 0; nt < 2; ++nt) {
    float s = lacc[nt];
    s += __shfl_xor(s, 16);
    s += __shfl_xor(s, 32);
    linv[nt] = 1.0f / s;
  }

  // O^T C-layout: col(l16)=qrow, row(quad*4+r)=d -> contiguous float4.
  float* outp = out + (size_t)(bh >> 3) * 1024 * 1024 + (bh & 7) * 128;
#pragma unroll
  for (int nt = 0; nt < 2; ++nt) {
    const int qrow = qw + nt * 16 + l16;
#pragma unroll
    for (int dt = 0; dt < 8; ++dt) {
      float4 v;
      v.x = o[dt][nt][0] * linv[nt];
      v.y = o[dt][nt][1] * linv[nt];
      v.z = o[dt][nt][2] * linv[nt];
      v.w = o[dt][nt][3] * linv[nt];
      *(float4*)(outp + (size_t)qrow * 1024 + dt * 16 + quad * 4) = v;
    }
  }
}

// ---------------------------------------------------------------------------
extern "C" void kernel_launch(void* const* d_in, const int* in_sizes, int n_in,
                              void* d_out, int out_size, void* d_ws,
                              size_t ws_size, hipStream_t stream) {
  const float* X = (const float*)d_in[0];
  const float* Wq = (const float*)d_in[1];
  const float* bq = (const float*)d_in[2];
  const float* Wk = (const float*)d_in[3];
  const float* bk = (const float*)d_in[4];
  const float* Wv = (const float*)d_in[5];
  const float* bv = (const float*)d_in[6];
  float* out = (float*)d_out;

  char* ws = (char*)d_ws;
  u16* Xb  = (u16*)(ws);                         // 16 MB  bf16 X
  u16* Wtb = (u16*)(ws + (16u << 20));           //  6 MB  bf16 W^T x3
  u16* Qh  = (u16*)(ws + (22u << 20));           // 16 MB  [B,H,S,DH]
  u16* Kh  = (u16*)(ws + (38u << 20));           // 16 MB  [B,H,S,DH]
  u16* Vt  = (u16*)(ws + (54u << 20));           // 16 MB  [B,H,DH,S]

  prep_kernel<<<8192 + 3072, 256, 0, stream>>>((const float4*)X, Xb, Wq, Wk,
                                               Wv, Wtb);
  dim3 gg(64, 8, 3);
  gemm_qkv_kernel<<<gg, 256, 0, stream>>>(Xb, Wtb, bq, bk, bv, Qh, Kh, Vt);
  attn_kernel<<<2048, 64, 0, stream>>>(Qh, Kh, Vt, out);
}

// Round 4
// 202.204 us; speedup vs baseline: 1.4458x; 1.4458x over previous
//
#include <hip/hip_runtime.h>

// ---------------------------------------------------------------------------
// ANHPMultiHeadAttention: fused QKV projection + exp-scored causal attention
// B=8, S=1024, FEAT=HID=1024, H=8, DH=128.
//
// R4 changes vs R3 (R3 regressed both kernels; base = R2):
//  - GEMM: revert to R2 operand order/epilogue (R3's C^T swap cost +20 VGPR
//    -> occupancy cliff). New: BK=32 double-buffered single-barrier pipeline:
//    prefetch(i+1) issues right after the top barrier, so the vmcnt(0) drain
//    happens a full compute phase later (hidden latency).
//  - ATTN: back to LDS-shared staging (R3's per-wave global reads were
//    latency-bound). 1024 blocks x 4 waves, BQ=64 (wave owns 16 q-rows ->
//    acc 32 VGPR), BK=32, K+V double-buffered, ONE barrier per iter, packed
//    uint2 P-writes (S^T = MFMA(kf,qf)), O^T = MFMA(vf,pa) -> float4 stores,
//    all LDS xor-swizzled (<=2-way), per-wave causal tile skip, LPT+XCD
//    swizzle. 36KB LDS + <=128 VGPR -> 16 waves/CU (R2 had 8).
// ---------------------------------------------------------------------------

typedef __bf16 bf16x8 __attribute__((ext_vector_type(8)));
typedef float floatx4 __attribute__((ext_vector_type(4)));
typedef unsigned short u16;
typedef unsigned int u32;

#define RSCALE 0.08838834764831845f   // 1/sqrt(128)

__device__ __forceinline__ u16 f2b(float f) {       // fp32 -> bf16 bits, RNE
  union { float f; unsigned u; } v; v.f = f;
  return (u16)((v.u + 0x7FFFu + ((v.u >> 16) & 1u)) >> 16);
}

// async global->LDS, 16B per lane. LDS dst = wave-uniform base + lane*16.
__device__ __forceinline__ void gld_lds16(const void* g, void* l) {
  __builtin_amdgcn_global_load_lds(
      (const __attribute__((address_space(1))) unsigned*)g,
      (__attribute__((address_space(3))) unsigned*)l, 16, 0, 0);
}

#define MFMA16(a, b, c) __builtin_amdgcn_mfma_f32_16x16x32_bf16(a, b, c, 0, 0, 0)

// ---------------------------------------------------------------------------
// Kernel 1: prep = cast X (blocks 0..8191) + transpose W (blocks 8192..11263)
// ---------------------------------------------------------------------------
__global__ __launch_bounds__(256) void prep_kernel(
    const float4* __restrict__ X, u16* __restrict__ Xb,
    const float* __restrict__ Wq, const float* __restrict__ Wk,
    const float* __restrict__ Wv, u16* __restrict__ Wtb) {
  if (blockIdx.x < 8192) {
    unsigned i = blockIdx.x * 256u + threadIdx.x;
    float4 v = X[i];
    ushort4 o;
    o.x = f2b(v.x); o.y = f2b(v.y); o.z = f2b(v.z); o.w = f2b(v.w);
    *reinterpret_cast<ushort4*>(Xb + 4u * i) = o;
  } else {
    const int bid = blockIdx.x - 8192;          // 0..3071
    const int mat = bid >> 10;                  // 1024 blocks per matrix
    const int bx = bid & 31, by = (bid >> 5) & 31;
    const float* W = (mat == 0) ? Wq : (mat == 1) ? Wk : Wv;
    u16* Wt = Wtb + (size_t)mat * (1024u * 1024u);
    __shared__ u16 tile[32][33];
    const int x = threadIdx.x & 31, y = threadIdx.x >> 5;
    const int kt = bx * 32, nt = by * 32;
#pragma unroll
    for (int i = 0; i < 4; ++i)
      tile[y + 8 * i][x] = f2b(W[(size_t)(kt + y + 8 * i) * 1024 + nt + x]);
    __syncthreads();
#pragma unroll
    for (int i = 0; i < 4; ++i)
      Wt[(size_t)(nt + y + 8 * i) * 1024 + kt + x] = tile[x][y + 8 * i];
  }
}

// ---------------------------------------------------------------------------
// Kernel 2: QKV GEMM. 128x128 tile, BK=32, double-buffered single-barrier
// pipeline, xor-swizzled LDS (conflict-free). grid (64, 8, 3).
// Q,K stored [B,H,S,DH]; V stored [B,H,DH,S] (transposed).
// ---------------------------------------------------------------------------
__global__ __launch_bounds__(256, 4) void gemm_qkv_kernel(
    const u16* __restrict__ Xb, const u16* __restrict__ Wtb,
    const float* __restrict__ bq, const float* __restrict__ bk,
    const float* __restrict__ bv, u16* __restrict__ Qh, u16* __restrict__ Kh,
    u16* __restrict__ Vt) {
  const int mat = blockIdx.z;
  const u16* __restrict__ Wt = Wtb + (size_t)mat * (1024u * 1024u);
  const float* __restrict__ bias = (mat == 0) ? bq : (mat == 1) ? bk : bv;

  const int m0 = blockIdx.x * 128;
  const int n0 = blockIdx.y * 128;

  __shared__ u16 As[2][128 * 32];   // [m][k] 8KB per buf, 64B rows, swizzled
  __shared__ u16 Bs[2][128 * 32];   // [n][k]

  const int tid = threadIdx.x;
  const int wid = tid >> 6;
  const int lane = tid & 63;
  const int quad = lane >> 4;
  const int l16 = lane & 15;
  const int wm = (wid & 1) * 64;
  const int wn = (wid >> 1) * 64;

  const floatx4 z4 = {0.f, 0.f, 0.f, 0.f};
  floatx4 acc[4][4];
#pragma unroll
  for (int i = 0; i < 4; ++i)
#pragma unroll
    for (int j = 0; j < 4; ++j) acc[i][j] = z4;

  // staging: lane L covers row r0+(L>>2), 16B unit L&3; swizzled source unit
  // g = (L&3) ^ ((L>>4)&3)  (phys unit holds global unit g, s(row)=(row>>2)&3)
  const int srow = lane >> 2;
  const int sg = (lane & 3) ^ ((lane >> 4) & 3);

  auto stage = [&](int b, int k0) {
#pragma unroll
    for (int c = 0; c < 2; ++c) {
      const int r0 = wid * 32 + c * 16;
      gld_lds16(Xb + (size_t)(m0 + r0 + srow) * 1024 + k0 + sg * 8,
                As[b] + r0 * 32);
      gld_lds16(Wt + (size_t)(n0 + r0 + srow) * 1024 + k0 + sg * 8,
                Bs[b] + r0 * 32);
    }
  };

  stage(0, 0);
  const int phys = (quad ^ ((l16 >> 2) & 3)) * 8;   // read-side unit swizzle

  for (int i = 0; i < 32; ++i) {
    __syncthreads();                 // drains prefetch(i); frees buf (i-1)&1
    if (i < 31) stage((i + 1) & 1, (i + 1) * 32);

    const u16* __restrict__ Ab = As[i & 1];
    const u16* __restrict__ Bb = Bs[i & 1];
    bf16x8 af[4], bfr[4];
#pragma unroll
    for (int ii = 0; ii < 4; ++ii)
      af[ii] = *(const bf16x8*)(Ab + (wm + ii * 16 + l16) * 32 + phys);
#pragma unroll
    for (int j = 0; j < 4; ++j)
      bfr[j] = *(const bf16x8*)(Bb + (wn + j * 16 + l16) * 32 + phys);
#pragma unroll
    for (int ii = 0; ii < 4; ++ii)
#pragma unroll
      for (int j = 0; j < 4; ++j)
        acc[ii][j] = MFMA16(af[ii], bfr[j], acc[ii][j]);
  }

  // epilogue (R2-proven). C/D layout: col = l16 (n), row = quad*4 + reg (m).
  const int b = m0 >> 10;
  const int h = n0 >> 7;
  const int sbase = (m0 & 1023) + wm;
  float bv4[4];
#pragma unroll
  for (int j = 0; j < 4; ++j) bv4[j] = bias[n0 + wn + j * 16 + l16];

  if (mat < 2) {
    u16* outp = (mat == 0 ? Qh : Kh) + (size_t)(b * 8 + h) * 1024 * 128;
#pragma unroll
    for (int i = 0; i < 4; ++i)
#pragma unroll
      for (int j = 0; j < 4; ++j) {
        const int d = wn + j * 16 + l16;
#pragma unroll
        for (int r = 0; r < 4; ++r) {
          const int s = sbase + i * 16 + quad * 4 + r;
          outp[(size_t)s * 128 + d] = f2b(acc[i][j][r] + bv4[j]);
        }
      }
  } else {
    // V^T: out[((b*8+h)*128 + d)*1024 + s]; 4 regs = 4 consecutive s.
    u16* outp = Vt + (size_t)(b * 8 + h) * 128 * 1024;
#pragma unroll
    for (int i = 0; i < 4; ++i)
#pragma unroll
      for (int j = 0; j < 4; ++j) {
        const int d = wn + j * 16 + l16;
        const int s = sbase + i * 16 + quad * 4;
        ushort4 pk;
        pk.x = f2b(acc[i][j][0] + bv4[j]);
        pk.y = f2b(acc[i][j][1] + bv4[j]);
        pk.z = f2b(acc[i][j][2] + bv4[j]);
        pk.w = f2b(acc[i][j][3] + bv4[j]);
        *(ushort4*)(outp + (size_t)d * 1024 + s) = pk;
      }
  }
}

// ---------------------------------------------------------------------------
// Kernel 3: attention. grid 1024 (= 64 bh x 16 qtiles of 64), block 256
// (4 waves, each owns 16 q-rows). BK=32. K+V double-buffered, ONE barrier
// per iteration (prefetch i+1 issued right after it -> drain hidden behind
// compute). S^T = MFMA(kf,qf) -> packed uint2 P-writes; O^T = MFMA(vf,pa)
// -> float4 output stores. LDS xor-swizzled, <=2-way everywhere.
// ---------------------------------------------------------------------------
__global__ __launch_bounds__(256, 4) void attn_kernel(const u16* __restrict__ Qh,
                                                      const u16* __restrict__ Kh,
                                                      const u16* __restrict__ Vt,
                                                      float* __restrict__ out) {
  const int id = blockIdx.x;
  const int bh = (id & 7) * 8 + ((id >> 3) & 7);   // XCD x owns 8 heads
  const int qt = 15 - (id >> 6);                   // heavy tiles first (LPT)
  const int q0 = qt * 64;

  const int tid = threadIdx.x;
  const int wid = tid >> 6;
  const int lane = tid & 63;
  const int quad = lane >> 4;
  const int l16 = lane & 15;

  __shared__ u16 Ks[2][32 * 128];   // [key][d] 256B rows, xor16 units, 8KB ea
  __shared__ u16 Vs[2][128 * 32];   // [d][key] 64B rows, xor4(row>>2), 8KB ea
  __shared__ u16 Ps[4 * 16 * 32];   // per-wave [q][key] 64B rows, 4KB

  const u16* __restrict__ Qbase = Qh + (size_t)bh * 1024 * 128;
  const u16* __restrict__ Kbase = Kh + (size_t)bh * 1024 * 128;
  const u16* __restrict__ Vbase = Vt + (size_t)bh * 128 * 1024;

  const int qw = q0 + wid * 16;     // this wave's 16 q-rows
  const int qrow = qw + l16;

  // Q B-frags (for S^T = MFMA(kf,qf)): lane l16 = q, k = quad*8+j.
  bf16x8 qf[4];
#pragma unroll
  for (int c = 0; c < 4; ++c)
    qf[c] = *(const bf16x8*)(Qbase + (size_t)qrow * 128 + c * 32 + quad * 8);

  const floatx4 z4 = {0.f, 0.f, 0.f, 0.f};
  floatx4 o[8];
#pragma unroll
  for (int dt = 0; dt < 8; ++dt) o[dt] = z4;
  float lacc = 0.f;

  // staging address pieces
  const int krow = lane >> 4;                       // K: 4 rows / call
  const int kg = l16;                               // phys unit
  const int vrow = lane >> 2;                       // V: 16 rows / call
  const int vg = (lane & 3) ^ ((lane >> 4) & 3);    // swizzled source unit

  auto stage = [&](int b, int k0) {
#pragma unroll
    for (int c = 0; c < 2; ++c) {                   // K: 32 rows x 256B
      const int r0 = wid * 8 + c * 4;
      const int row = r0 + krow;
      gld_lds16(Kbase + (size_t)(k0 + row) * 128 + ((kg ^ (row & 15)) * 8),
                Ks[b] + r0 * 128);
    }
#pragma unroll
    for (int c = 0; c < 2; ++c) {                   // V: 128 rows x 64B
      const int r0 = wid * 32 + c * 16;
      gld_lds16(Vbase + (size_t)(r0 + vrow) * 1024 + k0 + vg * 8,
                Vs[b] + r0 * 32);
    }
  };

  const int n = (q0 + 64) >> 5;     // causal: 2..32 iterations
  stage(0, 0);

  const int s4 = (l16 >> 2) & 3;    // read-side swizzle key

  for (int i = 0; i < n; ++i) {
    const int k0 = i << 5;
    __syncthreads();                // drains prefetch(i); frees buf (i-1)&1
    if (i + 1 < n) stage((i + 1) & 1, k0 + 32);

    if (k0 <= qrow - l16 + 15) {    // wave-uniform: k0 < qw+16 -> live tile
      const u16* __restrict__ Kb = Ks[i & 1];
      const u16* __restrict__ Vb = Vs[i & 1];

      // S^T tiles: MFMA(kf, qf) -> col(l16)=q, row(quad*4+r)=key.
      floatx4 st[2];
#pragma unroll
      for (int f = 0; f < 2; ++f) {
        bf16x8 kf[4];
#pragma unroll
        for (int c = 0; c < 4; ++c)
          kf[c] = *(const bf16x8*)(Kb + (f * 16 + l16) * 128 +
                                   (((c * 4 + quad) ^ l16) * 8));
        st[f] = z4;
#pragma unroll
        for (int c = 0; c < 4; ++c) st[f] = MFMA16(kf[c], qf[c], st[f]);
      }

      // exp + causal mask + packed P write (8B, swizzled, 2-way max)
#pragma unroll
      for (int f = 0; f < 2; ++f) {
        const int kb = k0 + f * 16 + quad * 4;
        float p[4];
#pragma unroll
        for (int r = 0; r < 4; ++r) {
          const float e = fminf(__expf(st[f][r] * RSCALE), 85.f);
          p[r] = (kb + r > qrow) ? 0.f : __expf(e);
        }
        lacc += (p[0] + p[1]) + (p[2] + p[3]);
        uint2 pk;
        pk.x = (u32)f2b(p[0]) | ((u32)f2b(p[1]) << 16);
        pk.y = (u32)f2b(p[2]) | ((u32)f2b(p[3]) << 16);
        *(uint2*)((char*)Ps + wid * 1024 + l16 * 64 +
                  ((f * 2 + (quad >> 1)) ^ s4) * 16 + (quad & 1) * 8) = pk;
      }
      asm volatile("s_waitcnt lgkmcnt(0)" ::: "memory");  // own P ready

      // pa: lane l16 = q, k = quad*8+j keys (A/B-frag identical layout)
      const bf16x8 pa = *(const bf16x8*)((char*)Ps + wid * 1024 + l16 * 64 +
                                         (quad ^ s4) * 16);
      // O^T += MFMA(vf, pa): vf lane l16 = d-row, k = quad*8+j keys.
#pragma unroll
      for (int dt = 0; dt < 8; ++dt) {
        const bf16x8 vf = *(const bf16x8*)(Vb + (dt * 16 + l16) * 32 +
                                           (quad ^ s4) * 8);
        o[dt] = MFMA16(vf, pa, o[dt]);
      }
    }
  }

  // l reduce across quads (lanes sharing l16), then normalize + store.
  float s = lacc;
  s += __shfl_xor(s, 16);
  s += __shfl_xor(s, 32);
  const float linv = 1.0f / s;

  // O^T C-layout: col(l16) = q, row(quad*4+r) = d -> contiguous float4.
  float* outp = out + (size_t)(bh >> 3) * 1024 * 1024 + (bh & 7) * 128;
#pragma unroll
  for (int dt = 0; dt < 8; ++dt) {
    float4 v;
    v.x = o[dt][0] * linv;
    v.y = o[dt][1] * linv;
    v.z = o[dt][2] * linv;
    v.w = o[dt][3] * linv;
    *(float4*)(outp + (size_t)qrow * 1024 + dt * 16 + quad * 4) = v;
  }
}

// ---------------------------------------------------------------------------
extern "C" void kernel_launch(void* const* d_in, const int* in_sizes, int n_in,
                              void* d_out, int out_size, void* d_ws,
                              size_t ws_size, hipStream_t stream) {
  const float* X = (const float*)d_in[0];
  const float* Wq = (const float*)d_in[1];
  const float* bq = (const float*)d_in[2];
  const float* Wk = (const float*)d_in[3];
  const float* bk = (const float*)d_in[4];
  const float* Wv = (const float*)d_in[5];
  const float* bv = (const float*)d_in[6];
  float* out = (float*)d_out;

  char* ws = (char*)d_ws;
  u16* Xb  = (u16*)(ws);                         // 16 MB  bf16 X
  u16* Wtb = (u16*)(ws + (16u << 20));           //  6 MB  bf16 W^T x3
  u16* Qh  = (u16*)(ws + (22u << 20));           // 16 MB  [B,H,S,DH]
  u16* Kh  = (u16*)(ws + (38u << 20));           // 16 MB  [B,H,S,DH]
  u16* Vt  = (u16*)(ws + (54u << 20));           // 16 MB  [B,H,DH,S]

  prep_kernel<<<8192 + 3072, 256, 0, stream>>>((const float4*)X, Xb, Wq, Wk,
                                               Wv, Wtb);
  dim3 gg(64, 8, 3);
  gemm_qkv_kernel<<<gg, 256, 0, stream>>>(Xb, Wtb, bq, bk, bv, Qh, Kh, Vt);
  attn_kernel<<<1024, 256, 0, stream>>>(Qh, Kh, Vt, out);
}

// Round 5
// 198.682 us; speedup vs baseline: 1.4714x; 1.0177x over previous
//
#include <hip/hip_runtime.h>

// ---------------------------------------------------------------------------
// ANHPMultiHeadAttention: fused QKV projection + exp-scored causal attention
// B=8, S=1024, FEAT=HID=1024, H=8, DH=128.
//
// R5 changes vs R4:
//  - Evidence: 64B LDS rows cost ~4 extra cyc per ds_read_b128 regardless of
//    swizzle (R1/R4 = 6.29M conflicts, R2 128B rows = 0). All LDS rows are
//    now >=128B.
//  - GEMM: BK=64 (128B rows, R2's proven 0-conflict swizzle) + R4's proven
//    single-barrier double-buffer pipeline. 64KB LDS -> 2 blocks/CU.
//  - ATTN was HBM-bound: BQ=64 re-read K/V 278MB from HBM. Now BQ=128
//    (147MB) and ALL 512 blocks co-resident (72KB LDS, 2 blocks/CU) with
//    all 8 q-tiles of a bh pinned to one XCD (8 bh x 512KB = 4MB = L2) so
//    re-reads hit L2. Paired qt schedule balances per-CU work. BK=64,
//    K+V double-buffered, single barrier/iter, PV via 2KB/wave Ps in two
//    32-key half-chunks.
// ---------------------------------------------------------------------------

typedef __bf16 bf16x8 __attribute__((ext_vector_type(8)));
typedef float floatx4 __attribute__((ext_vector_type(4)));
typedef unsigned short u16;
typedef unsigned int u32;

#define RSCALE 0.08838834764831845f   // 1/sqrt(128)

__device__ __forceinline__ u16 f2b(float f) {       // fp32 -> bf16 bits, RNE
  union { float f; unsigned u; } v; v.f = f;
  return (u16)((v.u + 0x7FFFu + ((v.u >> 16) & 1u)) >> 16);
}

// async global->LDS, 16B per lane. LDS dst = wave-uniform base + lane*16.
__device__ __forceinline__ void gld_lds16(const void* g, void* l) {
  __builtin_amdgcn_global_load_lds(
      (const __attribute__((address_space(1))) unsigned*)g,
      (__attribute__((address_space(3))) unsigned*)l, 16, 0, 0);
}

#define MFMA16(a, b, c) __builtin_amdgcn_mfma_f32_16x16x32_bf16(a, b, c, 0, 0, 0)

// ---------------------------------------------------------------------------
// Kernel 1: prep = cast X (blocks 0..8191) + transpose W (blocks 8192..11263)
// ---------------------------------------------------------------------------
__global__ __launch_bounds__(256) void prep_kernel(
    const float4* __restrict__ X, u16* __restrict__ Xb,
    const float* __restrict__ Wq, const float* __restrict__ Wk,
    const float* __restrict__ Wv, u16* __restrict__ Wtb) {
  if (blockIdx.x < 8192) {
    unsigned i = blockIdx.x * 256u + threadIdx.x;
    float4 v = X[i];
    ushort4 o;
    o.x = f2b(v.x); o.y = f2b(v.y); o.z = f2b(v.z); o.w = f2b(v.w);
    *reinterpret_cast<ushort4*>(Xb + 4u * i) = o;
  } else {
    const int bid = blockIdx.x - 8192;          // 0..3071
    const int mat = bid >> 10;                  // 1024 blocks per matrix
    const int bx = bid & 31, by = (bid >> 5) & 31;
    const float* W = (mat == 0) ? Wq : (mat == 1) ? Wk : Wv;
    u16* Wt = Wtb + (size_t)mat * (1024u * 1024u);
    __shared__ u16 tile[32][33];
    const int x = threadIdx.x & 31, y = threadIdx.x >> 5;
    const int kt = bx * 32, nt = by * 32;
#pragma unroll
    for (int i = 0; i < 4; ++i)
      tile[y + 8 * i][x] = f2b(W[(size_t)(kt + y + 8 * i) * 1024 + nt + x]);
    __syncthreads();
#pragma unroll
    for (int i = 0; i < 4; ++i)
      Wt[(size_t)(nt + y + 8 * i) * 1024 + kt + x] = tile[x][y + 8 * i];
  }
}

// ---------------------------------------------------------------------------
// Kernel 2: QKV GEMM. 128x128 tile, BK=64 (128B rows, xor8 swizzle, proven
// 0 conflicts in R2), double-buffered single-barrier pipeline. grid (64,8,3).
// Q,K stored [B,H,S,DH]; V stored [B,H,DH,S] (transposed).
// ---------------------------------------------------------------------------
__global__ __launch_bounds__(256, 2) void gemm_qkv_kernel(
    const u16* __restrict__ Xb, const u16* __restrict__ Wtb,
    const float* __restrict__ bq, const float* __restrict__ bk,
    const float* __restrict__ bv, u16* __restrict__ Qh, u16* __restrict__ Kh,
    u16* __restrict__ Vt) {
  const int mat = blockIdx.z;
  const u16* __restrict__ Wt = Wtb + (size_t)mat * (1024u * 1024u);
  const float* __restrict__ bias = (mat == 0) ? bq : (mat == 1) ? bk : bv;

  const int m0 = blockIdx.x * 128;
  const int n0 = blockIdx.y * 128;

  __shared__ u16 As[2][128 * 64];   // [m][k] 16KB per buf, 128B rows
  __shared__ u16 Bs[2][128 * 64];   // [n][k]

  const int tid = threadIdx.x;
  const int wid = tid >> 6;
  const int lane = tid & 63;
  const int quad = lane >> 4;
  const int l16 = lane & 15;
  const int wm = (wid & 1) * 64;
  const int wn = (wid >> 1) * 64;

  const floatx4 z4 = {0.f, 0.f, 0.f, 0.f};
  floatx4 acc[4][4];
#pragma unroll
  for (int i = 0; i < 4; ++i)
#pragma unroll
    for (int j = 0; j < 4; ++j) acc[i][j] = z4;

  // staging (R2-proven): wave loads 32 rows A + 32 rows B; 8 rows (1KB)/call.
  const int srow = wid * 32;
  const int lrow = lane >> 3;                 // 0..7 within call
  const int gblk = (lane & 7) ^ lrow;         // xor8 swizzle

  auto stage = [&](int b, int k0) {
#pragma unroll
    for (int c = 0; c < 4; ++c) {
      const int row = srow + c * 8 + lrow;
      gld_lds16(Xb + (size_t)(m0 + row) * 1024 + k0 + gblk * 8,
                As[b] + (srow + c * 8) * 64);
      gld_lds16(Wt + (size_t)(n0 + row) * 1024 + k0 + gblk * 8,
                Bs[b] + (srow + c * 8) * 64);
    }
  };

  stage(0, 0);

  for (int i = 0; i < 16; ++i) {
    __syncthreads();                 // drains prefetch(i); frees buf (i-1)&1
    if (i < 15) stage((i + 1) & 1, (i + 1) * 64);

    const u16* __restrict__ Ab = As[i & 1];
    const u16* __restrict__ Bb = Bs[i & 1];
#pragma unroll
    for (int c = 0; c < 2; ++c) {
      const int phys = ((c * 4 + quad) ^ (l16 & 7)) * 8;
      bf16x8 af[4], bfr[4];
#pragma unroll
      for (int ii = 0; ii < 4; ++ii)
        af[ii] = *(const bf16x8*)(Ab + (wm + ii * 16 + l16) * 64 + phys);
#pragma unroll
      for (int j = 0; j < 4; ++j)
        bfr[j] = *(const bf16x8*)(Bb + (wn + j * 16 + l16) * 64 + phys);
#pragma unroll
      for (int ii = 0; ii < 4; ++ii)
#pragma unroll
        for (int j = 0; j < 4; ++j)
          acc[ii][j] = MFMA16(af[ii], bfr[j], acc[ii][j]);
    }
  }

  // epilogue (R2-proven). C/D layout: col = l16 (n), row = quad*4 + reg (m).
  const int b = m0 >> 10;
  const int h = n0 >> 7;
  const int sbase = (m0 & 1023) + wm;
  float bv4[4];
#pragma unroll
  for (int j = 0; j < 4; ++j) bv4[j] = bias[n0 + wn + j * 16 + l16];

  if (mat < 2) {
    u16* outp = (mat == 0 ? Qh : Kh) + (size_t)(b * 8 + h) * 1024 * 128;
#pragma unroll
    for (int i = 0; i < 4; ++i)
#pragma unroll
      for (int j = 0; j < 4; ++j) {
        const int d = wn + j * 16 + l16;
#pragma unroll
        for (int r = 0; r < 4; ++r) {
          const int s = sbase + i * 16 + quad * 4 + r;
          outp[(size_t)s * 128 + d] = f2b(acc[i][j][r] + bv4[j]);
        }
      }
  } else {
    // V^T: out[((b*8+h)*128 + d)*1024 + s]; 4 regs = 4 consecutive s.
    u16* outp = Vt + (size_t)(b * 8 + h) * 128 * 1024;
#pragma unroll
    for (int i = 0; i < 4; ++i)
#pragma unroll
      for (int j = 0; j < 4; ++j) {
        const int d = wn + j * 16 + l16;
        const int s = sbase + i * 16 + quad * 4;
        ushort4 pk;
        pk.x = f2b(acc[i][j][0] + bv4[j]);
        pk.y = f2b(acc[i][j][1] + bv4[j]);
        pk.z = f2b(acc[i][j][2] + bv4[j]);
        pk.w = f2b(acc[i][j][3] + bv4[j]);
        *(ushort4*)(outp + (size_t)d * 1024 + s) = pk;
      }
  }
}

// ---------------------------------------------------------------------------
// Kernel 3: attention. grid 512 (all co-resident: 2 blocks/CU), block 256
// (4 waves x 32 q-rows, BQ=128). BK=64, K+V double-buffered, ONE barrier per
// iteration. XCD pinning: xcd = id&7 owns bh in [8*xcd, 8*xcd+8) -> K+V
// working set 4MB = one XCD L2; q-tiles share it. qt pairing balances CUs.
// S^T = MFMA(kf,qf); PV in two 32-key half-chunks via 2KB/wave Ps;
// O^T = MFMA(vf,pa) -> float4 stores.
// ---------------------------------------------------------------------------
__global__ __launch_bounds__(256, 2) void attn_kernel(const u16* __restrict__ Qh,
                                                      const u16* __restrict__ Kh,
                                                      const u16* __restrict__ Vt,
                                                      float* __restrict__ out) {
  const int id = blockIdx.x;
  const int x = id & 7;               // XCD (blocks round-robin by id%8)
  const int j = id >> 3;              // 0..63 within XCD
  const int bh = x * 8 + (j & 7);     // 8 heads pinned per XCD
  // CU-paired qt schedule: pairs (7,0),(5,2),(6,1),(4,3) -> equal work/CU.
  const int QTMAP[8] = {7, 5, 6, 4, 0, 2, 1, 3};
  const int qt = QTMAP[j >> 3];
  const int q0 = qt * 128;

  const int tid = threadIdx.x;
  const int wid = tid >> 6;
  const int lane = tid & 63;
  const int quad = lane >> 4;
  const int l16 = lane & 15;

  __shared__ u16 Ks[2][64 * 128];   // [key][d] 256B rows, 16KB each
  __shared__ u16 Vs[2][128 * 64];   // [d][key] 128B rows, 16KB each
  __shared__ u16 Ps[4][32 * 32];    // per-wave [q][32-key half] 64B rows, 2KB

  const u16* __restrict__ Qbase = Qh + (size_t)bh * 1024 * 128;
  const u16* __restrict__ Kbase = Kh + (size_t)bh * 1024 * 128;
  const u16* __restrict__ Vbase = Vt + (size_t)bh * 128 * 1024;

  const int qw = q0 + wid * 32;     // this wave's 32 q-rows

  // Q B-frags (for S^T = MFMA(kf,qf)): lane l16 = q, k = quad*8+j.
  bf16x8 qf[2][4];
#pragma unroll
  for (int nt = 0; nt < 2; ++nt)
#pragma unroll
    for (int c = 0; c < 4; ++c)
      qf[nt][c] = *(const bf16x8*)(Qbase + (size_t)(qw + nt * 16 + l16) * 128 +
                                   c * 32 + quad * 8);

  const floatx4 z4 = {0.f, 0.f, 0.f, 0.f};
  floatx4 o[2][8];
#pragma unroll
  for (int nt = 0; nt < 2; ++nt)
#pragma unroll
    for (int dt = 0; dt < 8; ++dt) o[nt][dt] = z4;
  float lacc[2] = {0.f, 0.f};

  // staging: K 64 rows x 256B (wave: 16 rows, 4 rows/call);
  //          V 128 rows x 128B (wave: 32 rows, 8 rows/call).
  auto stage = [&](int b, int k0) {
#pragma unroll
    for (int c = 0; c < 4; ++c) {
      const int r0 = wid * 16 + c * 4;
      const int row = r0 + quad;                       // row & 15 = c*4+quad
      gld_lds16(Kbase + (size_t)(k0 + row) * 128 + ((l16 ^ (c * 4 + quad)) * 8),
                Ks[b] + r0 * 128);
    }
#pragma unroll
    for (int c = 0; c < 4; ++c) {
      const int r0 = wid * 32 + c * 8;
      const int row = r0 + (lane >> 3);                // row & 7 = lane>>3 &7
      gld_lds16(Vbase + (size_t)row * 1024 + k0 +
                    (((lane & 7) ^ ((lane >> 3) & 7)) * 8),
                Vs[b] + r0 * 64);
    }
  };

  const int n = (q0 + 128) >> 6;    // 64-key iterations: 2..16
  stage(0, 0);

  for (int i = 0; i < n; ++i) {
    const int k0 = i << 6;
    __syncthreads();                // drains prefetch(i); frees buf (i-1)&1
    if (i + 1 < n) stage((i + 1) & 1, k0 + 64);

    const u16* __restrict__ Kb = Ks[i & 1];
    const u16* __restrict__ Vb = Vs[i & 1];

#pragma unroll
    for (int half = 0; half < 2; ++half) {
      if (k0 + half * 32 > qw + 31) break;   // wave-uniform causal skip

      // QK for the half's two 16-key tiles; write P into Ps.
#pragma unroll
      for (int f2 = 0; f2 < 2; ++f2) {
        const int f = half * 2 + f2;
        bf16x8 kf[4];
#pragma unroll
        for (int c = 0; c < 4; ++c)
          kf[c] = *(const bf16x8*)(Kb + (f * 16 + l16) * 128 +
                                   (((c * 4 + quad) ^ l16) * 8));
        floatx4 st[2];
#pragma unroll
        for (int nt = 0; nt < 2; ++nt) {
          st[nt] = z4;
#pragma unroll
          for (int c = 0; c < 4; ++c) st[nt] = MFMA16(kf[c], qf[nt][c], st[nt]);
        }
        const int kb = k0 + f * 16 + quad * 4;
#pragma unroll
        for (int nt = 0; nt < 2; ++nt) {
          const int qrow = qw + nt * 16 + l16;
          float p[4];
#pragma unroll
          for (int r = 0; r < 4; ++r) {
            const float e = fminf(__expf(st[nt][r] * RSCALE), 85.f);
            p[r] = (kb + r > qrow) ? 0.f : __expf(e);
          }
          lacc[nt] += (p[0] + p[1]) + (p[2] + p[3]);
          uint2 pk;
          pk.x = (u32)f2b(p[0]) | ((u32)f2b(p[1]) << 16);
          pk.y = (u32)f2b(p[2]) | ((u32)f2b(p[3]) << 16);
          // Ps row = nt*16+l16 (64B); 16B unit u = f2*2+(quad>>1), sub=quad&1;
          // unit-swizzle u ^= (l16&3).
          *(uint2*)((char*)Ps[wid] + (nt * 16 + l16) * 64 +
                    (((f2 * 2 + (quad >> 1)) ^ (l16 & 3)) * 16) +
                    (quad & 1) * 8) = pk;
        }
      }
      asm volatile("s_waitcnt lgkmcnt(0)" ::: "memory");  // own P visible

      // PV for this 32-key half. pa: B[k=key][n=q], lane l16=q, unit=quad^s.
      bf16x8 pa[2];
#pragma unroll
      for (int nt = 0; nt < 2; ++nt)
        pa[nt] = *(const bf16x8*)((char*)Ps[wid] + (nt * 16 + l16) * 64 +
                                  ((quad ^ (l16 & 3)) * 16));
#pragma unroll
      for (int dt = 0; dt < 8; ++dt) {
        const bf16x8 vf = *(const bf16x8*)(
            Vb + (dt * 16 + l16) * 64 +
            (((half * 4 + quad) ^ (l16 & 7)) * 8));
        o[0][dt] = MFMA16(vf, pa[0], o[0][dt]);
        o[1][dt] = MFMA16(vf, pa[1], o[1][dt]);
      }
    }
  }

  // l reduce across quads (lanes sharing l16), normalize, store.
  float linv[2];
#pragma unroll
  for (int nt = 0; nt < 2; ++nt) {
    float s = lacc[nt];
    s += __shfl_xor(s, 16);
    s += __shfl_xor(s, 32);
    linv[nt] = 1.0f / s;
  }

  // O^T C-layout: col(l16)=q, row(quad*4+r)=d -> contiguous float4.
  float* outp = out + (size_t)(bh >> 3) * 1024 * 1024 + (bh & 7) * 128;
#pragma unroll
  for (int nt = 0; nt < 2; ++nt) {
    const int qrow = qw + nt * 16 + l16;
#pragma unroll
    for (int dt = 0; dt < 8; ++dt) {
      float4 v;
      v.x = o[nt][dt][0] * linv[nt];
      v.y = o[nt][dt][1] * linv[nt];
      v.z = o[nt][dt][2] * linv[nt];
      v.w = o[nt][dt][3] * linv[nt];
      *(float4*)(outp + (size_t)qrow * 1024 + dt * 16 + quad * 4) = v;
    }
  }
}

// ---------------------------------------------------------------------------
extern "C" void kernel_launch(void* const* d_in, const int* in_sizes, int n_in,
                              void* d_out, int out_size, void* d_ws,
                              size_t ws_size, hipStream_t stream) {
  const float* X = (const float*)d_in[0];
  const float* Wq = (const float*)d_in[1];
  const float* bq = (const float*)d_in[2];
  const float* Wk = (const float*)d_in[3];
  const float* bk = (const float*)d_in[4];
  const float* Wv = (const float*)d_in[5];
  const float* bv = (const float*)d_in[6];
  float* out = (float*)d_out;

  char* ws = (char*)d_ws;
  u16* Xb  = (u16*)(ws);                         // 16 MB  bf16 X
  u16* Wtb = (u16*)(ws + (16u << 20));           //  6 MB  bf16 W^T x3
  u16* Qh  = (u16*)(ws + (22u << 20));           // 16 MB  [B,H,S,DH]
  u16* Kh  = (u16*)(ws + (38u << 20));           // 16 MB  [B,H,S,DH]
  u16* Vt  = (u16*)(ws + (54u << 20));           // 16 MB  [B,H,DH,S]

  prep_kernel<<<8192 + 3072, 256, 0, stream>>>((const float4*)X, Xb, Wq, Wk,
                                               Wv, Wtb);
  dim3 gg(64, 8, 3);
  gemm_qkv_kernel<<<gg, 256, 0, stream>>>(Xb, Wtb, bq, bk, bv, Qh, Kh, Vt);
  attn_kernel<<<512, 256, 0, stream>>>(Qh, Kh, Vt, out);
}